// Round 18
// baseline (195.741 us; speedup 1.0000x reference)
//
#include <hip/hip_runtime.h>

#define BB 2
#define NTOK 21952      // 28^3
#define CC 96
#define WD 784          // 28*28
#define NSR 343         // 7^3
#define NKT 22          // key tiles of 16 (352 padded keys)
#define NPADK 9.f       // 352-343 zero-pad keys, each adds exp(0)=1 to lsum
#define NSITE 686       // BB*NSR
#define SCALE 0.25f
#define LN_EPS 1e-5f
#define WSA_N (6*16*24*64)   // 147456 h4 slots: [ct][ks][kt][lane]
#define WPA_N (18*6*64)      // 6912  h4 slots: [ct][kt][lane]
#define PSTR 192             // P row stride (q1|q2|K|V); lepe + y are planar
#define PLANE ((size_t)BB * NTOK)   // tokens per channel-group plane
#define VRP 18               // VR row pad (f32): 2-way max bank aliasing

typedef _Float16 half_t;
typedef __attribute__((ext_vector_type(2))) _Float16 h2;
typedef __attribute__((ext_vector_type(4))) _Float16 h4;
typedef __attribute__((ext_vector_type(8))) _Float16 h8;
typedef __attribute__((ext_vector_type(4))) float f32x4;
union HU { h8 v; h2 p[4]; };
union H4U { h4 v; h2 p[2]; };

__device__ __forceinline__ h2 pk2(float a, float b) {
    return __builtin_bit_cast(h2, __builtin_amdgcn_cvt_pkrtz(a, b));
}

// ---------------------------------------------------------------------------
// K0: pack weights into MFMA A-frag layouts (unchanged).
// ---------------------------------------------------------------------------
__global__ __launch_bounds__(256) void k_wt(
    const float* __restrict__ w, h4* __restrict__ WSA, h4* __restrict__ WPA,
    const float* __restrict__ lepe_w, const float* __restrict__ q1_w,
    const float* __restrict__ q2_w, const float* __restrict__ kv2_w,
    const float* __restrict__ cw, float* __restrict__ cwT)
{
    const int id = blockIdx.x * 256 + threadIdx.x;
    if (id < WSA_N) {
        const int lane = id & 63;
        const int kt = (id >> 6) % 24;
        const int ks = ((id >> 6) / 24) % 16;
        const int ct = (id >> 6) / 384;
        const int co = ct * 16 + (lane & 15);
        const int kb = ks * 384 + kt * 16 + 4 * (lane >> 4);
        const int p = kb / 96, c = kb % 96;
        float f[4];
#pragma unroll
        for (int i = 0; i < 4; i++)
            f[i] = w[(size_t)co * 6144 + (c + i) * 64 + p];
        H4U t; t.p[0] = pk2(f[0], f[1]); t.p[1] = pk2(f[2], f[3]);
        WSA[id] = t.v;
    } else if (id < WSA_N + WPA_N) {
        const int id2 = id - WSA_N;
        const int lane = id2 & 63;
        const int kt = (id2 >> 6) % 6;
        const int ct = (id2 >> 6) / 6;
        const int co = ct * 16 + (lane & 15);
        const int k = kt * 16 + 4 * (lane >> 4);
        const float* wrow;
        if (co < 96)       wrow = lepe_w + co * 96;
        else if (co < 144) wrow = q1_w + (co - 96) * 96;
        else if (co < 192) wrow = q2_w + (co - 144) * 96;
        else               wrow = kv2_w + (co - 192) * 96;
        float4 v = *(const float4*)(wrow + k);
        H4U t; t.p[0] = pk2(v.x, v.y); t.p[1] = pk2(v.z, v.w);
        WPA[id2] = t.v;
    } else if (id < WSA_N + WPA_N + 27 * 96) {
        const int id3 = id - WSA_N - WPA_N;
        const int tap = id3 / 96, c = id3 % 96;
        cwT[tap * 96 + c] = cw[c * 27 + tap];
    }
}

// ---------------------------------------------------------------------------
// K1: FUSED proj + SR conv (unchanged from R17 -- confirmed keeper).
// ---------------------------------------------------------------------------
__global__ __launch_bounds__(384) void k_proj_sra(
    const float* __restrict__ x, const h4* __restrict__ WPA,
    const float* __restrict__ lepe_b, float* __restrict__ P,
    float4* __restrict__ tl, const h4* __restrict__ WSA,
    float* __restrict__ pa)
{
    __shared__ h4 BX[1536];
    const int tid = threadIdx.x;

    if (blockIdx.x < 686) {
        // ---------------- proj ----------------
        const int blk = blockIdx.x;
        if (tid < 256) {
            for (int s = tid; s < 1536; s += 256) {
                int lane = s & 63;
                int kt = (s >> 6) % 6;
                int tt = (s >> 6) / 6;
                int tok = blk * 64 + tt * 16 + (lane & 15);
                int k0 = kt * 16 + 4 * (lane >> 4);
                float4 v = *(const float4*)(x + (size_t)tok * 96 + k0);
                H4U t; t.p[0] = pk2(v.x, v.y); t.p[1] = pk2(v.z, v.w);
                BX[s] = t.v;
            }
        }
        __syncthreads();
        if (tid >= 256) return;

        const int lane = tid & 63;
        const int wid = tid >> 6;

        h4 bx[24];
#pragma unroll
        for (int q = 0; q < 24; q++) bx[q] = BX[q * 64 + lane];

        for (int ct = wid; ct < 18; ct += 4) {
            f32x4 acc[4];
#pragma unroll
            for (int tt = 0; tt < 4; tt++) acc[tt] = (f32x4){0.f, 0.f, 0.f, 0.f};
#pragma unroll
            for (int kt = 0; kt < 6; kt++) {
                h4 wa = WPA[(ct * 6 + kt) * 64 + lane];
#pragma unroll
                for (int tt = 0; tt < 4; tt++)
                    acc[tt] = __builtin_amdgcn_mfma_f32_16x16x16f16(
                        wa, bx[tt * 6 + kt], acc[tt], 0, 0, 0);
            }
            if (ct < 6) {
                float4 b4 = *(const float4*)(lepe_b + ct * 16 + 4 * (lane >> 4));
                const size_t cg = ct * 4 + (lane >> 4);
#pragma unroll
                for (int tt = 0; tt < 4; tt++) {
                    int tok = blk * 64 + tt * 16 + (lane & 15);
                    tl[cg * PLANE + tok] =
                        make_float4(acc[tt][0] + b4.x, acc[tt][1] + b4.y,
                                    acc[tt][2] + b4.z, acc[tt][3] + b4.w);
                }
            } else {
#pragma unroll
                for (int tt = 0; tt < 4; tt++) {
                    int tok = blk * 64 + tt * 16 + (lane & 15);
                    *(float4*)(P + (size_t)tok * PSTR + (ct - 6) * 16
                               + 4 * (lane >> 4)) =
                        make_float4(acc[tt][0], acc[tt][1], acc[tt][2], acc[tt][3]);
                }
            }
        }
        return;
    }

    // ---------------- SR conv ----------------
    const int idx = blockIdx.x - 686;        // 0..687
    const int mb = idx % 43;
    const int ks = idx / 43;
    const int lane = tid & 63;
    const int ct = tid >> 6;                 // 0..5

    for (int s = tid; s < 24 * 64; s += 384) {
        int l = s & 63;
        int kt = s >> 6;
        int site = mb * 16 + (l & 15);
        if (site > NSITE - 1) site = NSITE - 1;
        int b = site / NSR, sloc = site % NSR;
        int si = sloc / 49, sj = (sloc / 7) % 7, sk = sloc % 7;
        int kg = ks * 384 + kt * 16 + 4 * (l >> 4);
        int p = kg / 96, c = kg % 96;
        int a = p >> 4, q = (p >> 2) & 3, r = p & 3;
        int n = (4 * si + a) * WD + (4 * sj + q) * 28 + (4 * sk + r);
        float4 v = *(const float4*)(x + ((size_t)b * NTOK + n) * 96 + c);
        H4U t; t.p[0] = pk2(v.x, v.y); t.p[1] = pk2(v.z, v.w);
        BX[s] = t.v;
    }
    __syncthreads();

    const int site_g = mb * 16 + (lane & 15);
    const h4* wb = WSA + (size_t)((ct * 16 + ks) * 24) * 64 + lane;

    f32x4 acc0 = (f32x4){0.f, 0.f, 0.f, 0.f};
    f32x4 acc1 = (f32x4){0.f, 0.f, 0.f, 0.f};
#pragma unroll
    for (int kp = 0; kp < 12; kp++) {
        h4 wa0 = wb[(2 * kp) * 64];
        h4 wa1 = wb[(2 * kp + 1) * 64];
        acc0 = __builtin_amdgcn_mfma_f32_16x16x16f16(
            wa0, BX[(2 * kp) * 64 + lane], acc0, 0, 0, 0);
        acc1 = __builtin_amdgcn_mfma_f32_16x16x16f16(
            wa1, BX[(2 * kp + 1) * 64 + lane], acc1, 0, 0, 0);
    }
    if (site_g < NSITE) {
        *(float4*)(pa + ((size_t)site_g * 16 + ks) * 96 + ct * 16
                   + 4 * (lane >> 4)) =
            make_float4(acc0[0] + acc1[0], acc0[1] + acc1[1],
                        acc0[2] + acc1[2], acc0[3] + acc1[3]);
    }
}

// ---------------------------------------------------------------------------
// K2b: reduce 16 partials + bias + LN + GELU + kv1 -> k1/v1 (unchanged).
// ---------------------------------------------------------------------------
__global__ __launch_bounds__(96) void k_sr_b(
    const float* __restrict__ pa, const float* __restrict__ sr_b,
    const float* __restrict__ norm_g, const float* __restrict__ norm_b,
    const float* __restrict__ kv1_w, float* __restrict__ k1,
    float* __restrict__ v1)
{
    __shared__ float xs_s[96];
    __shared__ float gx[96];
    const int s_g = blockIdx.x;
    const int b = s_g / NSR, s = s_g % NSR;
    const int co = threadIdx.x;

    const float* pp = pa + (size_t)s_g * 16 * 96 + co;
    float acc = sr_b[co];
#pragma unroll
    for (int ks = 0; ks < 16; ks++) acc += pp[ks * 96];
    xs_s[co] = acc;
    __syncthreads();

    float m = 0.f, m2 = 0.f;
    for (int c = 0; c < 96; c++) { float v = xs_s[c]; m += v; m2 += v * v; }
    m *= (1.f / 96.f);
    float var = m2 * (1.f / 96.f) - m * m;
    float t = (acc - m) * rsqrtf(var + LN_EPS) * norm_g[co] + norm_b[co];
    gx[co] = 0.5f * t * (1.f + erff(t * 0.70710678118654752f));
    __syncthreads();

    const float4* w4 = (const float4*)(kv1_w + co * 96);
    const float4* g4 = (const float4*)gx;
    float a2 = 0.f;
#pragma unroll
    for (int c = 0; c < 24; c++) {
        float4 w = w4[c]; float4 g = g4[c];
        a2 += g.x * w.x + g.y * w.y + g.z * w.z + g.w * w.w;
    }
    int pair = co / 48, h = (co % 48) / 16, e = co % 16;
    float* dst = pair ? v1 : k1;
    dst[(((size_t)b * 3 + h) * NSR + s) * 16 + e] = a2;
}

// ---------------------------------------------------------------------------
// MFMA attention core (v_mfma_f32_16x16x16_f16, swapped operands).
// ---------------------------------------------------------------------------
__device__ __forceinline__ void attn_mfma_core(
    const h4* __restrict__ KA, const h4* __restrict__ VA, int lane,
    h4 qb, f32x4& o, float& lsum)
{
    o = (f32x4){0.f, 0.f, 0.f, 0.f};
    lsum = 0.f;
    for (int t = 0; t < NKT; t++) {
        h4 ka = KA[t * 64 + lane];
        f32x4 s = __builtin_amdgcn_mfma_f32_16x16x16f16(
            ka, qb, (f32x4){0.f, 0.f, 0.f, 0.f}, 0, 0, 0);
        float p0 = __expf(s[0]), p1 = __expf(s[1]);
        float p2 = __expf(s[2]), p3 = __expf(s[3]);
        lsum += (p0 + p1) + (p2 + p3);
        H4U pb;
        pb.p[0] = pk2(p0, p1);
        pb.p[1] = pk2(p2, p3);
        h4 va = VA[t * 64 + lane];
        o = __builtin_amdgcn_mfma_f32_16x16x16f16(va, pb.v, o, 0, 0, 0);
    }
}

// build VA (A-frag of V^T) from row-major VR staged in LDS.
// slot s: lane l holds { dim = l&15, keys k0..k0+3 }, k0 = 16t + 4*(l>>4).
__device__ __forceinline__ void build_VA(
    const float* __restrict__ VR, h4* __restrict__ VA, int tid)
{
    for (int s = tid; s < NKT * 64; s += 512) {
        int t = s >> 6, l = s & 63;
        int dim = l & 15;
        int k0 = t * 16 + (l >> 4) * 4;
        float f0 = VR[(k0 + 0) * VRP + dim];
        float f1 = VR[(k0 + 1) * VRP + dim];
        float f2 = VR[(k0 + 2) * VRP + dim];
        float f3 = VR[(k0 + 3) * VRP + dim];
        H4U tmp; tmp.p[0] = pk2(f0, f1); tmp.p[1] = pk2(f2, f3);
        VA[s] = tmp.v;
    }
}

// ---------------------------------------------------------------------------
// K3: FUSED attention. V is staged ROW-MAJOR into LDS with coalesced float4
// loads (4 per key row), then transposed to the VA fragment via LDS reads --
// replaces 5632 scattered scalar f32 global gathers per block (the R17
// V-staging antipattern). VR rows padded to 18 f32 (<=2-way bank aliasing).
// blocks 0..515 = branch-1; 516..899 = branch-2.
// ---------------------------------------------------------------------------
__global__ __launch_bounds__(512) void k_attn(
    const float* __restrict__ P, const float* __restrict__ k1,
    const float* __restrict__ v1, float4* __restrict__ yp)
{
    __shared__ h4 KA[NKT * 64];
    __shared__ h4 VA[NKT * 64];
    __shared__ float VR[352 * VRP];

    if (blockIdx.x < 516) {
        // ---------------- branch 1: SR attention ----------------
        const int bh = blockIdx.x % 6;
        const int qg = blockIdx.x / 6;           // 0..85
        const int b = bh / 3, h = bh % 3;
        const float* ksrc = k1 + (size_t)bh * NSR * 16;
        const float* vsrc = v1 + (size_t)bh * NSR * 16;

        for (int s = threadIdx.x; s < NKT * 64; s += 512) {
            int t = s >> 6, l = s & 63;
            int key = t * 16 + (l & 15);
            int dg = (l >> 4) * 4;
            H4U tmp; tmp.p[0] = pk2(0.f, 0.f); tmp.p[1] = pk2(0.f, 0.f);
            if (key < NSR) {
                float4 v = *(const float4*)(ksrc + (size_t)key * 16 + dg);
                tmp.p[0] = pk2(v.x, v.y); tmp.p[1] = pk2(v.z, v.w);
            }
            KA[s] = tmp.v;
        }
        // stage V rows coalesced: 4 float4 per key
        for (int s = threadIdx.x; s < 352 * 4; s += 512) {
            int key = s >> 2, e = s & 3;
            float4 v = make_float4(0.f, 0.f, 0.f, 0.f);
            if (key < NSR) v = *(const float4*)(vsrc + (size_t)key * 16 + e * 4);
            float* r = VR + key * VRP + e * 4;
            r[0] = v.x; r[1] = v.y; r[2] = v.z; r[3] = v.w;
        }
        __syncthreads();
        build_VA(VR, VA, threadIdx.x);
        __syncthreads();

        const int lane = threadIdx.x & 63;
        const int wid = threadIdx.x >> 6;

        for (int qi = wid; qi < 16; qi += 8) {
            int qt = qg * 16 + qi;
            if (qt >= 1372) break;                  // wave-uniform
            int tok = qt * 16 + (lane & 15);
            float4 qv = *(const float4*)(P + ((size_t)b * NTOK + tok) * PSTR
                                         + h * 16 + (lane >> 4) * 4);
            H4U qb;
            qb.p[0] = pk2(qv.x * SCALE, qv.y * SCALE);
            qb.p[1] = pk2(qv.z * SCALE, qv.w * SCALE);

            f32x4 o; float lsum;
            attn_mfma_core(KA, VA, lane, qb.v, o, lsum);
            lsum += __shfl_xor(lsum, 16);
            lsum += __shfl_xor(lsum, 32);
            float inv = 1.f / (lsum - NPADK);
            yp[(size_t)(h * 4 + (lane >> 4)) * PLANE + (size_t)b * NTOK + tok] =
                make_float4(o[0] * inv, o[1] * inv, o[2] * inv, o[3] * inv);
        }
        return;
    }

    // ---------------- branch 2: windowed attention ----------------
    const int pb = blockIdx.x - 516;             // 0..383
    const int b = pb / 192;
    const int rem = pb % 192;
    const int h = rem / 64, win = rem % 64;
    const int wh = win >> 4, ww = (win >> 2) & 3, wd = win & 3;
    const int h0 = wh * 7, w0 = ww * 7, d0 = wd * 7;
    const size_t bOff = (size_t)b * NTOK;

    for (int s = threadIdx.x; s < NKT * 64; s += 512) {
        int t = s >> 6, l = s & 63;
        int key = t * 16 + (l & 15);
        int dg = (l >> 4) * 4;
        H4U tmp; tmp.p[0] = pk2(0.f, 0.f); tmp.p[1] = pk2(0.f, 0.f);
        if (key < NSR) {
            int a = key / 49, bw = (key / 7) % 7, cw = key % 7;
            int n = (h0 + a) * WD + (w0 + bw) * 28 + (d0 + cw);
            float4 v = *(const float4*)(P + (bOff + n) * PSTR + 96 + h * 16 + dg);
            tmp.p[0] = pk2(v.x, v.y); tmp.p[1] = pk2(v.z, v.w);
        }
        KA[s] = tmp.v;
    }
    // stage V rows coalesced: 4 float4 per key (window gather at f4 granularity)
    for (int s = threadIdx.x; s < 352 * 4; s += 512) {
        int key = s >> 2, e = s & 3;
        float4 v = make_float4(0.f, 0.f, 0.f, 0.f);
        if (key < NSR) {
            int a = key / 49, bw = (key / 7) % 7, cw = key % 7;
            int n = (h0 + a) * WD + (w0 + bw) * 28 + (d0 + cw);
            v = *(const float4*)(P + (bOff + n) * PSTR + 144 + h * 16 + e * 4);
        }
        float* r = VR + key * VRP + e * 4;
        r[0] = v.x; r[1] = v.y; r[2] = v.z; r[3] = v.w;
    }
    __syncthreads();
    build_VA(VR, VA, threadIdx.x);
    __syncthreads();

    const int lane = threadIdx.x & 63;
    const int wid = threadIdx.x >> 6;

    for (int qt = wid; qt < NKT; qt += 8) {
        int q = qt * 16 + (lane & 15);
        int qc = (q < NSR) ? q : (NSR - 1);
        int ai = qc / 49, bi = (qc / 7) % 7, ci = qc % 7;
        int tok = (h0 + ai) * WD + (w0 + bi) * 28 + (d0 + ci);
        float4 qv = *(const float4*)(P + (bOff + tok) * PSTR
                                     + 48 + h * 16 + (lane >> 4) * 4);
        H4U qb;
        qb.p[0] = pk2(qv.x * SCALE, qv.y * SCALE);
        qb.p[1] = pk2(qv.z * SCALE, qv.w * SCALE);

        f32x4 o; float lsum;
        attn_mfma_core(KA, VA, lane, qb.v, o, lsum);
        lsum += __shfl_xor(lsum, 16);
        lsum += __shfl_xor(lsum, 32);
        float inv = 1.f / (lsum - NPADK);
        if (q < NSR) {
            yp[(size_t)(12 + h * 4 + (lane >> 4)) * PLANE + bOff + tok] =
                make_float4(o[0] * inv, o[1] * inv, o[2] * inv, o[3] * inv);
        }
    }
}

// ---------------------------------------------------------------------------
// K5: LePE depthwise 3x3x3 conv over planar tl; yp += lepe (R13 version).
// ---------------------------------------------------------------------------
__global__ __launch_bounds__(128) void k_lepe(
    const float4* __restrict__ tl, const float* __restrict__ cwT,
    const float* __restrict__ cb, float4* __restrict__ yp)
{
    const int blk = blockIdx.x;              // 2*24*28 = 1344
    const int h = blk % 28;
    const int cg = (blk / 28) % 24;
    const int b = blk / (28 * 24);
    const int t = threadIdx.x;
    if (t >= 112) return;
    const int w = t >> 2;                    // 0..27
    const int dq = t & 3;                    // 0..3
    const int d0 = dq * 7;
    const int c4 = cg * 4;

    const float4* base = tl + (size_t)cg * PLANE + (size_t)b * NTOK;

    float4 bias = *(const float4*)(cb + c4);
    float4 acc[7];
#pragma unroll
    for (int j = 0; j < 7; j++) acc[j] = bias;

#pragma unroll
    for (int dh = -1; dh <= 1; dh++) {
        const int hh = h + dh;
        const bool hok = (unsigned)hh < 28u;

        float4 pv[3][9];
#pragma unroll
        for (int dwi = 0; dwi < 3; dwi++) {
            const int ww = w + dwi - 1;
            const bool pok = hok & ((unsigned)ww < 28u);
            const float4* pp = base + (pok ? (hh * WD + ww * 28)
                                           : (h * WD + w * 28));
#pragma unroll
            for (int k = 0; k < 9; k++) {
                const int d = d0 - 1 + k;
                const bool dok = (unsigned)d < 28u;
                float4 v = pp[dok ? d : 0];
                if (!dok) v = make_float4(0.f, 0.f, 0.f, 0.f);
                pv[dwi][k] = v;
            }
        }

#pragma unroll
        for (int dwi = 0; dwi < 3; dwi++) {
            const int ww = w + dwi - 1;
            const bool pok = hok & ((unsigned)ww < 28u);
            const float mp = pok ? 1.f : 0.f;
            const int tb = ((dh + 1) * 3 + dwi) * 3;
            float4 wm = *(const float4*)(cwT + (tb + 0) * 96 + c4);
            float4 w0v = *(const float4*)(cwT + (tb + 1) * 96 + c4);
            float4 wp = *(const float4*)(cwT + (tb + 2) * 96 + c4);
            wm.x *= mp; wm.y *= mp; wm.z *= mp; wm.w *= mp;
            w0v.x *= mp; w0v.y *= mp; w0v.z *= mp; w0v.w *= mp;
            wp.x *= mp; wp.y *= mp; wp.z *= mp; wp.w *= mp;
#pragma unroll
            for (int j = 0; j < 7; j++) {
                acc[j].x += pv[dwi][j].x * wm.x + pv[dwi][j + 1].x * w0v.x + pv[dwi][j + 2].x * wp.x;
                acc[j].y += pv[dwi][j].y * wm.y + pv[dwi][j + 1].y * w0v.y + pv[dwi][j + 2].y * wp.y;
                acc[j].z += pv[dwi][j].z * wm.z + pv[dwi][j + 1].z * w0v.z + pv[dwi][j + 2].z * wp.z;
                acc[j].w += pv[dwi][j].w * wm.w + pv[dwi][j + 1].w * w0v.w + pv[dwi][j + 2].w * wp.w;
            }
        }
    }

    float4* yb = yp + (size_t)cg * PLANE + (size_t)b * NTOK
               + h * WD + w * 28 + d0;
#pragma unroll
    for (int j = 0; j < 7; j++) {
        float4 cur = yb[j];
        cur.x += acc[j].x; cur.y += acc[j].y;
        cur.z += acc[j].z; cur.w += acc[j].w;
        yb[j] = cur;
    }
}

// ---------------------------------------------------------------------------
// K6: out = y @ proj_w^T + proj_b  — y read from planar yp.
// ---------------------------------------------------------------------------
__global__ __launch_bounds__(192) void k_out(
    const float4* __restrict__ yp, const float* __restrict__ proj_w,
    const float* __restrict__ proj_b, float* __restrict__ out)
{
    __shared__ h2 xh[48][68];
    __shared__ h2 wh[48][52];

    const int base = blockIdx.x * 64;
    const int j0 = blockIdx.y * 48;

    for (int it = threadIdx.x; it < 1536; it += 192) {
        int t = it & 63, cq = it >> 6;
        float4 v = yp[(size_t)cq * PLANE + base + t];
        xh[cq * 2 + 0][t] = pk2(v.x, v.y);
        xh[cq * 2 + 1][t] = pk2(v.z, v.w);
    }
    for (int it = threadIdx.x; it < 1152; it += 192) {
        int jl = it % 48, cq = it / 48;
        float4 v = *(const float4*)(proj_w + (size_t)(j0 + jl) * 96 + cq * 4);
        wh[cq * 2 + 0][jl] = pk2(v.x, v.y);
        wh[cq * 2 + 1][jl] = pk2(v.z, v.w);
    }
    __syncthreads();

    const int tq = threadIdx.x & 15;
    const int jq = threadIdx.x >> 4;
    float acc[4][4];
#pragma unroll
    for (int i = 0; i < 4; i++)
#pragma unroll
        for (int jj = 0; jj < 4; jj++) acc[i][jj] = 0.f;

    for (int cp = 0; cp < 48; cp++) {
        HU xv, wv;
        xv.v = *(const h8*)(&xh[cp][tq * 4]);
        wv.v = *(const h8*)(&wh[cp][jq * 4]);
#pragma unroll
        for (int i = 0; i < 4; i++)
#pragma unroll
            for (int jj = 0; jj < 4; jj++)
                acc[i][jj] = __builtin_amdgcn_fdot2(xv.p[i], wv.p[jj], acc[i][jj], false);
    }

    float4 bias = *(const float4*)(proj_b + j0 + jq * 4);
#pragma unroll
    for (int i = 0; i < 4; i++) {
        int t = base + tq * 4 + i;
        float4 o = make_float4(acc[i][0] + bias.x, acc[i][1] + bias.y,
                               acc[i][2] + bias.z, acc[i][3] + bias.w);
        *(float4*)(out + (size_t)t * 96 + j0 + jq * 4) = o;
    }
}

extern "C" void kernel_launch(void* const* d_in, const int* in_sizes, int n_in,
                              void* d_out, int out_size, void* d_ws, size_t ws_size,
                              hipStream_t stream) {
    const float* x          = (const float*)d_in[0];
    const float* lepe_lin_w = (const float*)d_in[4];
    const float* lepe_lin_b = (const float*)d_in[5];
    const float* lepe_conv_w= (const float*)d_in[6];
    const float* lepe_conv_b= (const float*)d_in[7];
    const float* sr_w       = (const float*)d_in[8];
    const float* sr_b       = (const float*)d_in[9];
    const float* norm_g     = (const float*)d_in[10];
    const float* norm_b     = (const float*)d_in[11];
    const float* q1_w       = (const float*)d_in[12];
    const float* kv1_w      = (const float*)d_in[13];
    const float* q2_w       = (const float*)d_in[14];
    const float* kv2_w      = (const float*)d_in[15];
    const float* proj_w     = (const float*)d_in[16];
    const float* proj_b     = (const float*)d_in[17];

    float* P   = (float*)d_ws;                        // [B*N][192]
    float* tlf = P + (size_t)BB * NTOK * PSTR;        // planar lepe-in: 24 planes
    float* k1  = tlf + (size_t)24 * PLANE * 4;        // [B][3][343][16]
    float* v1  = k1 + (size_t)BB * 3 * NSR * 16;
    float* ypf = v1 + (size_t)BB * 3 * NSR * 16;      // planar y: 24 planes f4
    float* pa  = ypf + (size_t)24 * PLANE * 4;        // [686][16][96]
    float* WSAf= pa + (size_t)NSITE * 16 * 96;        // 147456 h4 = 294912 f
    float* WPAf= WSAf + (size_t)WSA_N * 2;            // 6912 h4 = 13824 f
    float* cwT = WPAf + (size_t)WPA_N * 2;            // [27][96]
    h4* WSA = (h4*)WSAf;
    h4* WPA = (h4*)WPAf;
    float4* tl = (float4*)tlf;
    float4* yp = (float4*)ypf;

    k_wt<<<614, 256, 0, stream>>>(sr_w, WSA, WPA, lepe_lin_w, q1_w, q2_w,
                                  kv2_w, lepe_conv_w, cwT);
    k_proj_sra<<<1374, 384, 0, stream>>>(x, WPA, lepe_lin_b, P, tl, WSA, pa);
    k_sr_b<<<NSITE, 96, 0, stream>>>(pa, sr_b, norm_g, norm_b, kv1_w, k1, v1);
    k_attn<<<900, 512, 0, stream>>>(P, k1, v1, yp);
    k_lepe<<<1344, 128, 0, stream>>>(tl, cwT, lepe_conv_b, yp);
    k_out<<<dim3(686, 2), 192, 0, stream>>>(yp, proj_w, proj_b, (float*)d_out);
}

// Round 19
// 192.133 us; speedup vs baseline: 1.0188x; 1.0188x over previous
//
#include <hip/hip_runtime.h>

#define BB 2
#define NTOK 21952      // 28^3
#define CC 96
#define WD 784          // 28*28
#define NSR 343         // 7^3
#define NKT 22          // key tiles of 16 (352 padded keys)
#define NPADK 9.f       // 352-343 zero-pad keys, each adds exp(0)=1 to lsum
#define NSITE 686       // BB*NSR
#define SCALE 0.25f
#define LN_EPS 1e-5f
#define WSA_N (6*16*24*64)   // 147456 h4 slots: [ct][ks][kt][lane]
#define WPA_N (18*6*64)      // 6912  h4 slots: [ct][kt][lane]
#define PSTR 192             // P row stride (q1|q2|K|V); lepe + y are planar
#define PLANE ((size_t)BB * NTOK)   // tokens per channel-group plane
#define VRP 18               // VR row pad (f32): 2-way max bank aliasing

typedef _Float16 half_t;
typedef __attribute__((ext_vector_type(2))) _Float16 h2;
typedef __attribute__((ext_vector_type(4))) _Float16 h4;
typedef __attribute__((ext_vector_type(8))) _Float16 h8;
typedef __attribute__((ext_vector_type(4))) float f32x4;
union HU { h8 v; h2 p[4]; };
union H4U { h4 v; h2 p[2]; };

__device__ __forceinline__ h2 pk2(float a, float b) {
    return __builtin_bit_cast(h2, __builtin_amdgcn_cvt_pkrtz(a, b));
}

// ---------------------------------------------------------------------------
// K0: pack weights into MFMA A-frag layouts (unchanged).
// ---------------------------------------------------------------------------
__global__ __launch_bounds__(256) void k_wt(
    const float* __restrict__ w, h4* __restrict__ WSA, h4* __restrict__ WPA,
    const float* __restrict__ lepe_w, const float* __restrict__ q1_w,
    const float* __restrict__ q2_w, const float* __restrict__ kv2_w,
    const float* __restrict__ cw, float* __restrict__ cwT)
{
    const int id = blockIdx.x * 256 + threadIdx.x;
    if (id < WSA_N) {
        const int lane = id & 63;
        const int kt = (id >> 6) % 24;
        const int ks = ((id >> 6) / 24) % 16;
        const int ct = (id >> 6) / 384;
        const int co = ct * 16 + (lane & 15);
        const int kb = ks * 384 + kt * 16 + 4 * (lane >> 4);
        const int p = kb / 96, c = kb % 96;
        float f[4];
#pragma unroll
        for (int i = 0; i < 4; i++)
            f[i] = w[(size_t)co * 6144 + (c + i) * 64 + p];
        H4U t; t.p[0] = pk2(f[0], f[1]); t.p[1] = pk2(f[2], f[3]);
        WSA[id] = t.v;
    } else if (id < WSA_N + WPA_N) {
        const int id2 = id - WSA_N;
        const int lane = id2 & 63;
        const int kt = (id2 >> 6) % 6;
        const int ct = (id2 >> 6) / 6;
        const int co = ct * 16 + (lane & 15);
        const int k = kt * 16 + 4 * (lane >> 4);
        const float* wrow;
        if (co < 96)       wrow = lepe_w + co * 96;
        else if (co < 144) wrow = q1_w + (co - 96) * 96;
        else if (co < 192) wrow = q2_w + (co - 144) * 96;
        else               wrow = kv2_w + (co - 192) * 96;
        float4 v = *(const float4*)(wrow + k);
        H4U t; t.p[0] = pk2(v.x, v.y); t.p[1] = pk2(v.z, v.w);
        WPA[id2] = t.v;
    } else if (id < WSA_N + WPA_N + 27 * 96) {
        const int id3 = id - WSA_N - WPA_N;
        const int tap = id3 / 96, c = id3 % 96;
        cwT[tap * 96 + c] = cw[c * 27 + tap];
    }
}

// ---------------------------------------------------------------------------
// K1: FUSED proj + SR conv (unchanged).
// ---------------------------------------------------------------------------
__global__ __launch_bounds__(384) void k_proj_sra(
    const float* __restrict__ x, const h4* __restrict__ WPA,
    const float* __restrict__ lepe_b, float* __restrict__ P,
    float4* __restrict__ tl, const h4* __restrict__ WSA,
    float* __restrict__ pa)
{
    __shared__ h4 BX[1536];
    const int tid = threadIdx.x;

    if (blockIdx.x < 686) {
        // ---------------- proj ----------------
        const int blk = blockIdx.x;
        if (tid < 256) {
            for (int s = tid; s < 1536; s += 256) {
                int lane = s & 63;
                int kt = (s >> 6) % 6;
                int tt = (s >> 6) / 6;
                int tok = blk * 64 + tt * 16 + (lane & 15);
                int k0 = kt * 16 + 4 * (lane >> 4);
                float4 v = *(const float4*)(x + (size_t)tok * 96 + k0);
                H4U t; t.p[0] = pk2(v.x, v.y); t.p[1] = pk2(v.z, v.w);
                BX[s] = t.v;
            }
        }
        __syncthreads();
        if (tid >= 256) return;

        const int lane = tid & 63;
        const int wid = tid >> 6;

        h4 bx[24];
#pragma unroll
        for (int q = 0; q < 24; q++) bx[q] = BX[q * 64 + lane];

        for (int ct = wid; ct < 18; ct += 4) {
            f32x4 acc[4];
#pragma unroll
            for (int tt = 0; tt < 4; tt++) acc[tt] = (f32x4){0.f, 0.f, 0.f, 0.f};
#pragma unroll
            for (int kt = 0; kt < 6; kt++) {
                h4 wa = WPA[(ct * 6 + kt) * 64 + lane];
#pragma unroll
                for (int tt = 0; tt < 4; tt++)
                    acc[tt] = __builtin_amdgcn_mfma_f32_16x16x16f16(
                        wa, bx[tt * 6 + kt], acc[tt], 0, 0, 0);
            }
            if (ct < 6) {
                float4 b4 = *(const float4*)(lepe_b + ct * 16 + 4 * (lane >> 4));
                const size_t cg = ct * 4 + (lane >> 4);
#pragma unroll
                for (int tt = 0; tt < 4; tt++) {
                    int tok = blk * 64 + tt * 16 + (lane & 15);
                    tl[cg * PLANE + tok] =
                        make_float4(acc[tt][0] + b4.x, acc[tt][1] + b4.y,
                                    acc[tt][2] + b4.z, acc[tt][3] + b4.w);
                }
            } else {
#pragma unroll
                for (int tt = 0; tt < 4; tt++) {
                    int tok = blk * 64 + tt * 16 + (lane & 15);
                    *(float4*)(P + (size_t)tok * PSTR + (ct - 6) * 16
                               + 4 * (lane >> 4)) =
                        make_float4(acc[tt][0], acc[tt][1], acc[tt][2], acc[tt][3]);
                }
            }
        }
        return;
    }

    // ---------------- SR conv ----------------
    const int idx = blockIdx.x - 686;        // 0..687
    const int mb = idx % 43;
    const int ks = idx / 43;
    const int lane = tid & 63;
    const int ct = tid >> 6;                 // 0..5

    for (int s = tid; s < 24 * 64; s += 384) {
        int l = s & 63;
        int kt = s >> 6;
        int site = mb * 16 + (l & 15);
        if (site > NSITE - 1) site = NSITE - 1;
        int b = site / NSR, sloc = site % NSR;
        int si = sloc / 49, sj = (sloc / 7) % 7, sk = sloc % 7;
        int kg = ks * 384 + kt * 16 + 4 * (l >> 4);
        int p = kg / 96, c = kg % 96;
        int a = p >> 4, q = (p >> 2) & 3, r = p & 3;
        int n = (4 * si + a) * WD + (4 * sj + q) * 28 + (4 * sk + r);
        float4 v = *(const float4*)(x + ((size_t)b * NTOK + n) * 96 + c);
        H4U t; t.p[0] = pk2(v.x, v.y); t.p[1] = pk2(v.z, v.w);
        BX[s] = t.v;
    }
    __syncthreads();

    const int site_g = mb * 16 + (lane & 15);
    const h4* wb = WSA + (size_t)((ct * 16 + ks) * 24) * 64 + lane;

    f32x4 acc0 = (f32x4){0.f, 0.f, 0.f, 0.f};
    f32x4 acc1 = (f32x4){0.f, 0.f, 0.f, 0.f};
#pragma unroll
    for (int kp = 0; kp < 12; kp++) {
        h4 wa0 = wb[(2 * kp) * 64];
        h4 wa1 = wb[(2 * kp + 1) * 64];
        acc0 = __builtin_amdgcn_mfma_f32_16x16x16f16(
            wa0, BX[(2 * kp) * 64 + lane], acc0, 0, 0, 0);
        acc1 = __builtin_amdgcn_mfma_f32_16x16x16f16(
            wa1, BX[(2 * kp + 1) * 64 + lane], acc1, 0, 0, 0);
    }
    if (site_g < NSITE) {
        *(float4*)(pa + ((size_t)site_g * 16 + ks) * 96 + ct * 16
                   + 4 * (lane >> 4)) =
            make_float4(acc0[0] + acc1[0], acc0[1] + acc1[1],
                        acc0[2] + acc1[2], acc0[3] + acc1[3]);
    }
}

// ---------------------------------------------------------------------------
// K2b: reduce 16 partials + bias + LN + GELU + kv1 -> k1/v1 (unchanged).
// ---------------------------------------------------------------------------
__global__ __launch_bounds__(96) void k_sr_b(
    const float* __restrict__ pa, const float* __restrict__ sr_b,
    const float* __restrict__ norm_g, const float* __restrict__ norm_b,
    const float* __restrict__ kv1_w, float* __restrict__ k1,
    float* __restrict__ v1)
{
    __shared__ float xs_s[96];
    __shared__ float gx[96];
    const int s_g = blockIdx.x;
    const int b = s_g / NSR, s = s_g % NSR;
    const int co = threadIdx.x;

    const float* pp = pa + (size_t)s_g * 16 * 96 + co;
    float acc = sr_b[co];
#pragma unroll
    for (int ks = 0; ks < 16; ks++) acc += pp[ks * 96];
    xs_s[co] = acc;
    __syncthreads();

    float m = 0.f, m2 = 0.f;
    for (int c = 0; c < 96; c++) { float v = xs_s[c]; m += v; m2 += v * v; }
    m *= (1.f / 96.f);
    float var = m2 * (1.f / 96.f) - m * m;
    float t = (acc - m) * rsqrtf(var + LN_EPS) * norm_g[co] + norm_b[co];
    gx[co] = 0.5f * t * (1.f + erff(t * 0.70710678118654752f));
    __syncthreads();

    const float4* w4 = (const float4*)(kv1_w + co * 96);
    const float4* g4 = (const float4*)gx;
    float a2 = 0.f;
#pragma unroll
    for (int c = 0; c < 24; c++) {
        float4 w = w4[c]; float4 g = g4[c];
        a2 += g.x * w.x + g.y * w.y + g.z * w.z + g.w * w.w;
    }
    int pair = co / 48, h = (co % 48) / 16, e = co % 16;
    float* dst = pair ? v1 : k1;
    dst[(((size_t)b * 3 + h) * NSR + s) * 16 + e] = a2;
}

// ---------------------------------------------------------------------------
// MFMA attention core (v_mfma_f32_16x16x16_f16, swapped operands).
// ---------------------------------------------------------------------------
__device__ __forceinline__ void attn_mfma_core(
    const h4* __restrict__ KA, const h4* __restrict__ VA, int lane,
    h4 qb, f32x4& o, float& lsum)
{
    o = (f32x4){0.f, 0.f, 0.f, 0.f};
    lsum = 0.f;
    for (int t = 0; t < NKT; t++) {
        h4 ka = KA[t * 64 + lane];
        f32x4 s = __builtin_amdgcn_mfma_f32_16x16x16f16(
            ka, qb, (f32x4){0.f, 0.f, 0.f, 0.f}, 0, 0, 0);
        float p0 = __expf(s[0]), p1 = __expf(s[1]);
        float p2 = __expf(s[2]), p3 = __expf(s[3]);
        lsum += (p0 + p1) + (p2 + p3);
        H4U pb;
        pb.p[0] = pk2(p0, p1);
        pb.p[1] = pk2(p2, p3);
        h4 va = VA[t * 64 + lane];
        o = __builtin_amdgcn_mfma_f32_16x16x16f16(va, pb.v, o, 0, 0, 0);
    }
}

// build VA (A-frag of V^T) from row-major VR staged in LDS.
__device__ __forceinline__ void build_VA(
    const float* __restrict__ VR, h4* __restrict__ VA, int tid)
{
    for (int s = tid; s < NKT * 64; s += 512) {
        int t = s >> 6, l = s & 63;
        int dim = l & 15;
        int k0 = t * 16 + (l >> 4) * 4;
        float f0 = VR[(k0 + 0) * VRP + dim];
        float f1 = VR[(k0 + 1) * VRP + dim];
        float f2 = VR[(k0 + 2) * VRP + dim];
        float f3 = VR[(k0 + 3) * VRP + dim];
        H4U tmp; tmp.p[0] = pk2(f0, f1); tmp.p[1] = pk2(f2, f3);
        VA[s] = tmp.v;
    }
}

// ---------------------------------------------------------------------------
// K3: FUSED attention. Branch-1 staging amortized 2x: q-groups 86 -> 43,
// each block computes 32 q-tiles (4 per wave) against one staged K/V --
// halves branch-1's redundant K/V staging (same K/V was staged by all 86
// blocks of a bh). Branch-2 windows have distinct K/V (unchanged).
// blocks 0..257 = branch-1 (6 bh x 43 qg); 258..641 = branch-2.
// ---------------------------------------------------------------------------
__global__ __launch_bounds__(512) void k_attn(
    const float* __restrict__ P, const float* __restrict__ k1,
    const float* __restrict__ v1, float4* __restrict__ yp)
{
    __shared__ h4 KA[NKT * 64];
    __shared__ h4 VA[NKT * 64];
    __shared__ float VR[352 * VRP];

    if (blockIdx.x < 258) {
        // ---------------- branch 1: SR attention ----------------
        const int bh = blockIdx.x % 6;
        const int qg = blockIdx.x / 6;           // 0..42
        const int b = bh / 3, h = bh % 3;
        const float* ksrc = k1 + (size_t)bh * NSR * 16;
        const float* vsrc = v1 + (size_t)bh * NSR * 16;

        for (int s = threadIdx.x; s < NKT * 64; s += 512) {
            int t = s >> 6, l = s & 63;
            int key = t * 16 + (l & 15);
            int dg = (l >> 4) * 4;
            H4U tmp; tmp.p[0] = pk2(0.f, 0.f); tmp.p[1] = pk2(0.f, 0.f);
            if (key < NSR) {
                float4 v = *(const float4*)(ksrc + (size_t)key * 16 + dg);
                tmp.p[0] = pk2(v.x, v.y); tmp.p[1] = pk2(v.z, v.w);
            }
            KA[s] = tmp.v;
        }
        for (int s = threadIdx.x; s < 352 * 4; s += 512) {
            int key = s >> 2, e = s & 3;
            float4 v = make_float4(0.f, 0.f, 0.f, 0.f);
            if (key < NSR) v = *(const float4*)(vsrc + (size_t)key * 16 + e * 4);
            float* r = VR + key * VRP + e * 4;
            r[0] = v.x; r[1] = v.y; r[2] = v.z; r[3] = v.w;
        }
        __syncthreads();
        build_VA(VR, VA, threadIdx.x);
        __syncthreads();

        const int lane = threadIdx.x & 63;
        const int wid = threadIdx.x >> 6;

        for (int qi = wid; qi < 32; qi += 8) {
            int qt = qg * 32 + qi;
            if (qt >= 1372) break;                  // wave-uniform
            int tok = qt * 16 + (lane & 15);
            float4 qv = *(const float4*)(P + ((size_t)b * NTOK + tok) * PSTR
                                         + h * 16 + (lane >> 4) * 4);
            H4U qb;
            qb.p[0] = pk2(qv.x * SCALE, qv.y * SCALE);
            qb.p[1] = pk2(qv.z * SCALE, qv.w * SCALE);

            f32x4 o; float lsum;
            attn_mfma_core(KA, VA, lane, qb.v, o, lsum);
            lsum += __shfl_xor(lsum, 16);
            lsum += __shfl_xor(lsum, 32);
            float inv = 1.f / (lsum - NPADK);
            yp[(size_t)(h * 4 + (lane >> 4)) * PLANE + (size_t)b * NTOK + tok] =
                make_float4(o[0] * inv, o[1] * inv, o[2] * inv, o[3] * inv);
        }
        return;
    }

    // ---------------- branch 2: windowed attention ----------------
    const int pb = blockIdx.x - 258;             // 0..383
    const int b = pb / 192;
    const int rem = pb % 192;
    const int h = rem / 64, win = rem % 64;
    const int wh = win >> 4, ww = (win >> 2) & 3, wd = win & 3;
    const int h0 = wh * 7, w0 = ww * 7, d0 = wd * 7;
    const size_t bOff = (size_t)b * NTOK;

    for (int s = threadIdx.x; s < NKT * 64; s += 512) {
        int t = s >> 6, l = s & 63;
        int key = t * 16 + (l & 15);
        int dg = (l >> 4) * 4;
        H4U tmp; tmp.p[0] = pk2(0.f, 0.f); tmp.p[1] = pk2(0.f, 0.f);
        if (key < NSR) {
            int a = key / 49, bw = (key / 7) % 7, cw = key % 7;
            int n = (h0 + a) * WD + (w0 + bw) * 28 + (d0 + cw);
            float4 v = *(const float4*)(P + (bOff + n) * PSTR + 96 + h * 16 + dg);
            tmp.p[0] = pk2(v.x, v.y); tmp.p[1] = pk2(v.z, v.w);
        }
        KA[s] = tmp.v;
    }
    for (int s = threadIdx.x; s < 352 * 4; s += 512) {
        int key = s >> 2, e = s & 3;
        float4 v = make_float4(0.f, 0.f, 0.f, 0.f);
        if (key < NSR) {
            int a = key / 49, bw = (key / 7) % 7, cw = key % 7;
            int n = (h0 + a) * WD + (w0 + bw) * 28 + (d0 + cw);
            v = *(const float4*)(P + (bOff + n) * PSTR + 144 + h * 16 + e * 4);
        }
        float* r = VR + key * VRP + e * 4;
        r[0] = v.x; r[1] = v.y; r[2] = v.z; r[3] = v.w;
    }
    __syncthreads();
    build_VA(VR, VA, threadIdx.x);
    __syncthreads();

    const int lane = threadIdx.x & 63;
    const int wid = threadIdx.x >> 6;

    for (int qt = wid; qt < NKT; qt += 8) {
        int q = qt * 16 + (lane & 15);
        int qc = (q < NSR) ? q : (NSR - 1);
        int ai = qc / 49, bi = (qc / 7) % 7, ci = qc % 7;
        int tok = (h0 + ai) * WD + (w0 + bi) * 28 + (d0 + ci);
        float4 qv = *(const float4*)(P + (bOff + tok) * PSTR
                                     + 48 + h * 16 + (lane >> 4) * 4);
        H4U qb;
        qb.p[0] = pk2(qv.x * SCALE, qv.y * SCALE);
        qb.p[1] = pk2(qv.z * SCALE, qv.w * SCALE);

        f32x4 o; float lsum;
        attn_mfma_core(KA, VA, lane, qb.v, o, lsum);
        lsum += __shfl_xor(lsum, 16);
        lsum += __shfl_xor(lsum, 32);
        float inv = 1.f / (lsum - NPADK);
        if (q < NSR) {
            yp[(size_t)(12 + h * 4 + (lane >> 4)) * PLANE + bOff + tok] =
                make_float4(o[0] * inv, o[1] * inv, o[2] * inv, o[3] * inv);
        }
    }
}

// ---------------------------------------------------------------------------
// K5: LePE depthwise 3x3x3 conv over planar tl; yp += lepe (R13 version).
// ---------------------------------------------------------------------------
__global__ __launch_bounds__(128) void k_lepe(
    const float4* __restrict__ tl, const float* __restrict__ cwT,
    const float* __restrict__ cb, float4* __restrict__ yp)
{
    const int blk = blockIdx.x;              // 2*24*28 = 1344
    const int h = blk % 28;
    const int cg = (blk / 28) % 24;
    const int b = blk / (28 * 24);
    const int t = threadIdx.x;
    if (t >= 112) return;
    const int w = t >> 2;                    // 0..27
    const int dq = t & 3;                    // 0..3
    const int d0 = dq * 7;
    const int c4 = cg * 4;

    const float4* base = tl + (size_t)cg * PLANE + (size_t)b * NTOK;

    float4 bias = *(const float4*)(cb + c4);
    float4 acc[7];
#pragma unroll
    for (int j = 0; j < 7; j++) acc[j] = bias;

#pragma unroll
    for (int dh = -1; dh <= 1; dh++) {
        const int hh = h + dh;
        const bool hok = (unsigned)hh < 28u;

        float4 pv[3][9];
#pragma unroll
        for (int dwi = 0; dwi < 3; dwi++) {
            const int ww = w + dwi - 1;
            const bool pok = hok & ((unsigned)ww < 28u);
            const float4* pp = base + (pok ? (hh * WD + ww * 28)
                                           : (h * WD + w * 28));
#pragma unroll
            for (int k = 0; k < 9; k++) {
                const int d = d0 - 1 + k;
                const bool dok = (unsigned)d < 28u;
                float4 v = pp[dok ? d : 0];
                if (!dok) v = make_float4(0.f, 0.f, 0.f, 0.f);
                pv[dwi][k] = v;
            }
        }

#pragma unroll
        for (int dwi = 0; dwi < 3; dwi++) {
            const int ww = w + dwi - 1;
            const bool pok = hok & ((unsigned)ww < 28u);
            const float mp = pok ? 1.f : 0.f;
            const int tb = ((dh + 1) * 3 + dwi) * 3;
            float4 wm = *(const float4*)(cwT + (tb + 0) * 96 + c4);
            float4 w0v = *(const float4*)(cwT + (tb + 1) * 96 + c4);
            float4 wp = *(const float4*)(cwT + (tb + 2) * 96 + c4);
            wm.x *= mp; wm.y *= mp; wm.z *= mp; wm.w *= mp;
            w0v.x *= mp; w0v.y *= mp; w0v.z *= mp; w0v.w *= mp;
            wp.x *= mp; wp.y *= mp; wp.z *= mp; wp.w *= mp;
#pragma unroll
            for (int j = 0; j < 7; j++) {
                acc[j].x += pv[dwi][j].x * wm.x + pv[dwi][j + 1].x * w0v.x + pv[dwi][j + 2].x * wp.x;
                acc[j].y += pv[dwi][j].y * wm.y + pv[dwi][j + 1].y * w0v.y + pv[dwi][j + 2].y * wp.y;
                acc[j].z += pv[dwi][j].z * wm.z + pv[dwi][j + 1].z * w0v.z + pv[dwi][j + 2].z * wp.z;
                acc[j].w += pv[dwi][j].w * wm.w + pv[dwi][j + 1].w * w0v.w + pv[dwi][j + 2].w * wp.w;
            }
        }
    }

    float4* yb = yp + (size_t)cg * PLANE + (size_t)b * NTOK
               + h * WD + w * 28 + d0;
#pragma unroll
    for (int j = 0; j < 7; j++) {
        float4 cur = yb[j];
        cur.x += acc[j].x; cur.y += acc[j].y;
        cur.z += acc[j].z; cur.w += acc[j].w;
        yb[j] = cur;
    }
}

// ---------------------------------------------------------------------------
// K6: out = y @ proj_w^T + proj_b  — y read from planar yp.
// ---------------------------------------------------------------------------
__global__ __launch_bounds__(192) void k_out(
    const float4* __restrict__ yp, const float* __restrict__ proj_w,
    const float* __restrict__ proj_b, float* __restrict__ out)
{
    __shared__ h2 xh[48][68];
    __shared__ h2 wh[48][52];

    const int base = blockIdx.x * 64;
    const int j0 = blockIdx.y * 48;

    for (int it = threadIdx.x; it < 1536; it += 192) {
        int t = it & 63, cq = it >> 6;
        float4 v = yp[(size_t)cq * PLANE + base + t];
        xh[cq * 2 + 0][t] = pk2(v.x, v.y);
        xh[cq * 2 + 1][t] = pk2(v.z, v.w);
    }
    for (int it = threadIdx.x; it < 1152; it += 192) {
        int jl = it % 48, cq = it / 48;
        float4 v = *(const float4*)(proj_w + (size_t)(j0 + jl) * 96 + cq * 4);
        wh[cq * 2 + 0][jl] = pk2(v.x, v.y);
        wh[cq * 2 + 1][jl] = pk2(v.z, v.w);
    }
    __syncthreads();

    const int tq = threadIdx.x & 15;
    const int jq = threadIdx.x >> 4;
    float acc[4][4];
#pragma unroll
    for (int i = 0; i < 4; i++)
#pragma unroll
        for (int jj = 0; jj < 4; jj++) acc[i][jj] = 0.f;

    for (int cp = 0; cp < 48; cp++) {
        HU xv, wv;
        xv.v = *(const h8*)(&xh[cp][tq * 4]);
        wv.v = *(const h8*)(&wh[cp][jq * 4]);
#pragma unroll
        for (int i = 0; i < 4; i++)
#pragma unroll
            for (int jj = 0; jj < 4; jj++)
                acc[i][jj] = __builtin_amdgcn_fdot2(xv.p[i], wv.p[jj], acc[i][jj], false);
    }

    float4 bias = *(const float4*)(proj_b + j0 + jq * 4);
#pragma unroll
    for (int i = 0; i < 4; i++) {
        int t = base + tq * 4 + i;
        float4 o = make_float4(acc[i][0] + bias.x, acc[i][1] + bias.y,
                               acc[i][2] + bias.z, acc[i][3] + bias.w);
        *(float4*)(out + (size_t)t * 96 + j0 + jq * 4) = o;
    }
}

extern "C" void kernel_launch(void* const* d_in, const int* in_sizes, int n_in,
                              void* d_out, int out_size, void* d_ws, size_t ws_size,
                              hipStream_t stream) {
    const float* x          = (const float*)d_in[0];
    const float* lepe_lin_w = (const float*)d_in[4];
    const float* lepe_lin_b = (const float*)d_in[5];
    const float* lepe_conv_w= (const float*)d_in[6];
    const float* lepe_conv_b= (const float*)d_in[7];
    const float* sr_w       = (const float*)d_in[8];
    const float* sr_b       = (const float*)d_in[9];
    const float* norm_g     = (const float*)d_in[10];
    const float* norm_b     = (const float*)d_in[11];
    const float* q1_w       = (const float*)d_in[12];
    const float* kv1_w      = (const float*)d_in[13];
    const float* q2_w       = (const float*)d_in[14];
    const float* kv2_w      = (const float*)d_in[15];
    const float* proj_w     = (const float*)d_in[16];
    const float* proj_b     = (const float*)d_in[17];

    float* P   = (float*)d_ws;                        // [B*N][192]
    float* tlf = P + (size_t)BB * NTOK * PSTR;        // planar lepe-in: 24 planes
    float* k1  = tlf + (size_t)24 * PLANE * 4;        // [B][3][343][16]
    float* v1  = k1 + (size_t)BB * 3 * NSR * 16;
    float* ypf = v1 + (size_t)BB * 3 * NSR * 16;      // planar y: 24 planes f4
    float* pa  = ypf + (size_t)24 * PLANE * 4;        // [686][16][96]
    float* WSAf= pa + (size_t)NSITE * 16 * 96;        // 147456 h4 = 294912 f
    float* WPAf= WSAf + (size_t)WSA_N * 2;            // 6912 h4 = 13824 f
    float* cwT = WPAf + (size_t)WPA_N * 2;            // [27][96]
    h4* WSA = (h4*)WSAf;
    h4* WPA = (h4*)WPAf;
    float4* tl = (float4*)tlf;
    float4* yp = (float4*)ypf;

    k_wt<<<614, 256, 0, stream>>>(sr_w, WSA, WPA, lepe_lin_w, q1_w, q2_w,
                                  kv2_w, lepe_conv_w, cwT);
    k_proj_sra<<<1374, 384, 0, stream>>>(x, WPA, lepe_lin_b, P, tl, WSA, pa);
    k_sr_b<<<NSITE, 96, 0, stream>>>(pa, sr_b, norm_g, norm_b, kv1_w, k1, v1);
    k_attn<<<642, 512, 0, stream>>>(P, k1, v1, yp);
    k_lepe<<<1344, 128, 0, stream>>>(tl, cwT, lepe_conv_b, yp);
    k_out<<<dim3(686, 2), 192, 0, stream>>>(yp, proj_w, proj_b, (float*)d_out);
}